// Round 5
// baseline (35.526 us; speedup 1.0000x reference)
//
#include <hip/hip_runtime.h>
#include <math.h>

#define KG_B    16384
#define KG_D    128
#define KG_NR   24
#define KG_TM   32                        // elements per block (padded segment quantum)
#define KG_BPAD (KG_B + KG_NR * KG_TM)    // 17152
#define KG_NGRP (KG_BPAD / KG_TM)         // 536

// ws ints: perm[BPAD] | cnt[24] | cur[24] | pbase[24] ; floats: partials[64] | terms[BPAD]
#define WS_CNT   KG_BPAD
#define WS_CUR   (KG_BPAD + 24)
#define WS_PBASE (KG_BPAD + 48)
#define WS_FLT   (KG_BPAD + 72)
#define WS_PART  WS_FLT
#define WS_TERMS (WS_FLT + 64)

typedef __attribute__((ext_vector_type(8))) short bf16x8;
typedef __attribute__((ext_vector_type(4))) float f32x4;

__device__ __forceinline__ unsigned bf16r(float f) {
    return (__float_as_uint(f) + 0x8000u) >> 16;
}
__device__ __forceinline__ unsigned pack2(float lo, float hi) {
    return bf16r(lo) | (bf16r(hi) << 16);
}

// ---- K0: perm = -1 everywhere, zero the 48 counters ----
__global__ __launch_bounds__(256) void kg_init(int* wsi) {
    const int i = blockIdx.x * 256 + threadIdx.x;
    if (i < KG_BPAD) wsi[i] = -1;
    if (blockIdx.x == 0 && threadIdx.x < 48) wsi[WS_CNT + threadIdx.x] = 0;
}

// ---- K1: parallel histogram (LDS per block, 24 global atomics/block) ----
__global__ __launch_bounds__(1024) void kg_hist(const int* __restrict__ r, int* wsi) {
    __shared__ int hc[24];
    const int t = threadIdx.x;
    if (t < 24) hc[t] = 0;
    __syncthreads();
    atomicAdd(&hc[r[blockIdx.x * 1024 + t]], 1);
    __syncthreads();
    if (t < 24 && hc[t] > 0) atomicAdd(&wsi[WS_CNT + t], hc[t]);
}

// ---- K2: padded exclusive scan over 24 bins ----
__global__ void kg_scan(int* wsi) {
    int run = 0;
    for (int k = 0; k < KG_NR; ++k) {
        wsi[WS_PBASE + k] = run;
        run += (wsi[WS_CNT + k] + KG_TM - 1) & ~(KG_TM - 1);
    }
}

// ---- K3: parallel scatter (per-block LDS ranks + one global claim/bin) ----
__global__ __launch_bounds__(1024) void kg_scatter(const int* __restrict__ r, int* wsi) {
    __shared__ int hc[24], hb[24];
    const int t = threadIdx.x;
    if (t < 24) hc[t] = 0;
    __syncthreads();
    const int i = blockIdx.x * 1024 + t;
    const int k = r[i];
    const int rank = atomicAdd(&hc[k], 1);
    __syncthreads();
    if (t < 24 && hc[t] > 0)
        hb[t] = wsi[WS_PBASE + t] + atomicAdd(&wsi[WS_CUR + t], hc[t]);
    __syncthreads();
    wsi[hb[k] + rank] = i;
}

// ---- K4: MFMA main. Block = 32 same-relation elements, 4 waves:
//      wave w -> rows (w&1)*16, cols (w>>1)*64. ----
__global__ __launch_bounds__(256, 2) void kg_main(
    const float* __restrict__ ent, const float* __restrict__ rel,
    const float* __restrict__ M,   const int* __restrict__ h,
    const int* __restrict__ r,     const int* __restrict__ pt,
    const int* __restrict__ nt,    const int* __restrict__ perm,
    float* __restrict__ terms)
{
    __shared__ unsigned short sX[3 * KG_TM * KG_D];   // 24 KB bf16, row-XOR-swizzled
    __shared__ unsigned short sW[KG_D * KG_D];        // 32 KB bf16 W^T, col-XOR-swizzled
    __shared__ float sScr[2][KG_TM][4];               // 1 KB score partials

    const int tid   = threadIdx.x;
    const int slot0 = blockIdx.x * KG_TM;
    const int p0    = perm[slot0];
    if (p0 < 0) {                          // fully padded / unused trailing group
        if (tid < KG_TM) terms[slot0 + tid] = 0.f;
        return;
    }
    const int rb = __builtin_amdgcn_readfirstlane(r[p0]);

    // ---- stage X: thread t -> row g=t>>3, 16 dims at e0=(t&7)*16, 3 products ----
    {
        const int g  = tid >> 3;
        const int e0 = (tid & 7) * 16;
        const int pg = perm[slot0 + g];
        const int bb = pg < 0 ? p0 : pg;
        const int idx3[3] = { h[bb], pt[bb], nt[bb] };
        const int sw = (g & 7) << 3;
#pragma unroll
        for (int t3 = 0; t3 < 3; ++t3) {
            const float* src = ent + (size_t)idx3[t3] * KG_D + e0;
            const float4 f0 = ((const float4*)src)[0];
            const float4 f1 = ((const float4*)src)[1];
            const float4 f2 = ((const float4*)src)[2];
            const float4 f3 = ((const float4*)src)[3];
            uint4 u0, u1;
            u0.x = pack2(f0.x, f0.y); u0.y = pack2(f0.z, f0.w);
            u0.z = pack2(f1.x, f1.y); u0.w = pack2(f1.z, f1.w);
            u1.x = pack2(f2.x, f2.y); u1.y = pack2(f2.z, f2.w);
            u1.z = pack2(f3.x, f3.y); u1.w = pack2(f3.z, f3.w);
            unsigned short* base = sX + t3 * (KG_TM * KG_D) + g * KG_D;
            *(uint4*)(base + ((e0    ) ^ sw)) = u0;
            *(uint4*)(base + ((e0 + 8) ^ sw)) = u1;
        }
    }
    // ---- stage W^T: thread t -> W row e=t>>1, cols (t&1)*64 .. +63 ----
    {
        const int e  = tid >> 1;
        const int c0 = (tid & 1) * 64;
        const float* src = M + ((size_t)rb << 14) + (size_t)e * KG_D + c0;
#pragma unroll
        for (int i4 = 0; i4 < 16; ++i4) {
            const float4 w4 = ((const float4*)src)[i4];
            const int cb = c0 + i4 * 4;
            sW[(cb + 0) * KG_D + (e ^ (((cb + 0) & 7) << 3))] = (unsigned short)bf16r(w4.x);
            sW[(cb + 1) * KG_D + (e ^ (((cb + 1) & 7) << 3))] = (unsigned short)bf16r(w4.y);
            sW[(cb + 2) * KG_D + (e ^ (((cb + 2) & 7) << 3))] = (unsigned short)bf16r(w4.z);
            sW[(cb + 3) * KG_D + (e ^ (((cb + 3) & 7) << 3))] = (unsigned short)bf16r(w4.w);
        }
    }
    __syncthreads();

    const int l   = tid & 63;
    const int w   = tid >> 6;
    const int rt  = w & 1;                 // row-tile (16 rows)
    const int chs = w >> 1;                // column half (64 cols)
    const int li  = l & 15;
    const int kq  = l >> 4;

    const int ar  = rt * 16 + li;          // A row = element index in block
    const int asw = (ar & 7) << 3;

    f32x4 acc[3][4];
#pragma unroll
    for (int t3 = 0; t3 < 3; ++t3)
#pragma unroll
        for (int n = 0; n < 4; ++n) acc[t3][n] = (f32x4)0.f;

#pragma unroll
    for (int kk = 0; kk < 4; ++kk) {       // K chunks of 32
        const int e0 = kk * 32 + kq * 8;
        bf16x8 af[3];
#pragma unroll
        for (int t3 = 0; t3 < 3; ++t3)
            af[t3] = *(const bf16x8*)&sX[t3 * (KG_TM * KG_D) + ar * KG_D + (e0 ^ asw)];
#pragma unroll
        for (int n = 0; n < 4; ++n) {
            const int col = chs * 64 + n * 16 + li;
            const bf16x8 bfr = *(const bf16x8*)&sW[col * KG_D + (e0 ^ ((col & 7) << 3))];
            acc[0][n] = __builtin_amdgcn_mfma_f32_16x16x32_bf16(af[0], bfr, acc[0][n], 0, 0, 0);
            acc[1][n] = __builtin_amdgcn_mfma_f32_16x16x32_bf16(af[1], bfr, acc[1][n], 0, 0, 0);
            acc[2][n] = __builtin_amdgcn_mfma_f32_16x16x32_bf16(af[2], bfr, acc[2][n], 0, 0, 0);
        }
    }

    // ---- epilogue: C/D layout col=lane&15, row=(lane>>4)*4+reg ----
    float ps[4] = {0,0,0,0}, ns[4] = {0,0,0,0}, sq[4] = {0,0,0,0};
    const float* relrow = rel + (size_t)rb * KG_D + chs * 64;
#pragma unroll
    for (int n = 0; n < 4; ++n) {
        const float rv = relrow[n * 16 + li];
#pragma unroll
        for (int j = 0; j < 4; ++j) {
            const float va = acc[0][n][j];
            const float vp = acc[1][n][j];
            const float vn = acc[2][n][j];
            const float s  = va + rv;
            const float dp = s - vp;
            const float dn = s - vn;
            ps[j] += dp * dp;
            ns[j] += dn * dn;
            sq[j] += va * va + vp * vp + vn * vn + rv * rv;
        }
    }
#pragma unroll
    for (int j = 0; j < 4; ++j)
#pragma unroll
        for (int m = 1; m < 16; m <<= 1) {
            ps[j] += __shfl_xor(ps[j], m);
            ns[j] += __shfl_xor(ns[j], m);
            sq[j] += __shfl_xor(sq[j], m);
        }

    if (li == 0) {
#pragma unroll
        for (int j = 0; j < 4; ++j) {
            const int row = rt * 16 + kq * 4 + j;
            sScr[chs][row][0] = ps[j];
            sScr[chs][row][1] = ns[j];
            sScr[chs][row][2] = sq[j];
        }
    }
    __syncthreads();

    if (tid < KG_TM) {
        const int row = tid;
        const float P = sScr[0][row][0] + sScr[1][row][0];
        const float N = sScr[0][row][1] + sScr[1][row][1];
        const float S = sScr[0][row][2] + sScr[1][row][2];
        const int pg = perm[slot0 + row];
        float term = 0.f;
        if (pg >= 0) {
            const float x = P - N;                              // pos - neg
            term = fmaxf(x, 0.f) + log1pf(expf(-fabsf(x)))      // softplus
                 + 5e-6f * S;                                   // lambda/2 * l2
        }
        terms[slot0 + row] = term;
    }
}

// ---- K5/K6: deterministic two-stage reduction ----
__global__ __launch_bounds__(256) void kg_reduce1(const float* __restrict__ terms,
                                                  float* __restrict__ partials) {
    __shared__ float s[256];
    const int t = threadIdx.x;
    float acc = 0.f;
    for (int i = blockIdx.x * 256 + t; i < KG_BPAD; i += 64 * 256) acc += terms[i];
    s[t] = acc;
    __syncthreads();
    for (int off = 128; off > 0; off >>= 1) {
        if (t < off) s[t] += s[t + off];
        __syncthreads();
    }
    if (t == 0) partials[blockIdx.x] = s[0];
}

__global__ __launch_bounds__(64) void kg_reduce2(const float* __restrict__ partials,
                                                 float* __restrict__ out) {
    float v = partials[threadIdx.x];
    for (int off = 32; off > 0; off >>= 1) v += __shfl_down(v, off);
    if (threadIdx.x == 0) out[0] = v * (1.0f / (float)KG_B);
}

extern "C" void kernel_launch(void* const* d_in, const int* in_sizes, int n_in,
                              void* d_out, int out_size, void* d_ws, size_t ws_size,
                              hipStream_t stream) {
    const float* ent = (const float*)d_in[0];
    const float* rel = (const float*)d_in[1];
    const float* M   = (const float*)d_in[2];
    const int*   h   = (const int*)d_in[3];
    const int*   r   = (const int*)d_in[4];
    const int*   pt  = (const int*)d_in[5];
    const int*   nt  = (const int*)d_in[6];

    int*   wsi      = (int*)d_ws;
    float* partials = (float*)d_ws + WS_PART;
    float* terms    = (float*)d_ws + WS_TERMS;
    float* out      = (float*)d_out;

    kg_init   <<<(KG_BPAD + 255) / 256, 256, 0, stream>>>(wsi);
    kg_hist   <<<KG_B / 1024, 1024, 0, stream>>>(r, wsi);
    kg_scan   <<<1, 1, 0, stream>>>(wsi);
    kg_scatter<<<KG_B / 1024, 1024, 0, stream>>>(r, wsi);
    kg_main   <<<KG_NGRP, 256, 0, stream>>>(ent, rel, M, h, r, pt, nt, wsi, terms);
    kg_reduce1<<<64, 256, 0, stream>>>(terms, partials);
    kg_reduce2<<<1, 64, 0, stream>>>(partials, out);
}

// Round 6
// 32.205 us; speedup vs baseline: 1.1031x; 1.1031x over previous
//
#include <hip/hip_runtime.h>
#include <math.h>

#define KG_B    16384
#define KG_D    128
#define KG_NR   24
#define KG_TM   32                        // elements per block
#define KG_BPAD (KG_B + KG_NR * KG_TM)    // 17152
#define KG_NGRP (KG_BPAD / KG_TM)         // 536

// ws ints: perm[BPAD] ; floats (after): bsum[KG_NGRP]
#define WS_BSUM KG_BPAD

typedef __attribute__((ext_vector_type(8))) short bf16x8;
typedef __attribute__((ext_vector_type(4))) float f32x4;

__device__ __forceinline__ unsigned bf16r(float f) {
    return (__float_as_uint(f) + 0x8000u) >> 16;
}
__device__ __forceinline__ unsigned pack2(float lo, float hi) {
    return bf16r(lo) | (bf16r(hi) << 16);
}

// ---- K1: fused sort. One 1024-thread block: per-wave LDS histogram ->
//      scan (padded to KG_TM) -> scatter -> pad fill. All counters in LDS. ----
__global__ __launch_bounds__(1024) void kg_sort(const int* __restrict__ r,
                                                int* __restrict__ perm) {
    __shared__ int cntw[16][25];     // per-wave counters (padded rows)
    __shared__ int basew[16][25];
    __shared__ int pbase_s[24];
    __shared__ int cnt_tot[24];
    __shared__ int total_s;

    const int t = threadIdx.x;
    const int w = t >> 6;

    int* cz = &cntw[0][0];
    for (int i = t; i < 16 * 25; i += 1024) cz[i] = 0;
    __syncthreads();

    int kt[16];
#pragma unroll
    for (int j = 0; j < 16; ++j) kt[j] = r[j * 1024 + t];
#pragma unroll
    for (int j = 0; j < 16; ++j) atomicAdd(&cntw[w][kt[j]], 1);
    __syncthreads();

    if (t < 24) {                     // scan the 16 wave-counts per relation
        int s = 0;
        for (int w2 = 0; w2 < 16; ++w2) { basew[w2][t] = s; s += cntw[w2][t]; }
        cnt_tot[t] = s;
    }
    __syncthreads();
    if (t == 0) {                     // padded exclusive scan over relations
        int run = 0;
        for (int k = 0; k < 24; ++k) {
            pbase_s[k] = run;
            run += (cnt_tot[k] + (KG_TM - 1)) & ~(KG_TM - 1);
        }
        total_s = run;
    }
    __syncthreads();
    if (t < 24)
        for (int w2 = 0; w2 < 16; ++w2) basew[w2][t] += pbase_s[t];
    for (int i = t; i < 16 * 25; i += 1024) cz[i] = 0;   // reuse cntw as cur
    __syncthreads();

#pragma unroll
    for (int j = 0; j < 16; ++j) {
        const int k = kt[j];
        const int pos = basew[w][k] + atomicAdd(&cntw[w][k], 1);
        perm[pos] = j * 1024 + t;
    }
    __syncthreads();

    if (t < 24) {                     // pad gaps inside each segment
        const int e0 = pbase_s[t] + cnt_tot[t];
        const int e1 = pbase_s[t] + ((cnt_tot[t] + (KG_TM - 1)) & ~(KG_TM - 1));
        for (int p = e0; p < e1; ++p) perm[p] = -1;
    }
    for (int i = total_s + t; i < KG_BPAD; i += 1024) perm[i] = -1;
}

// ---- K2: MFMA main. Block = 32 same-relation elements, 4 waves:
//      wave w -> rows (w&1)*16, cols (w>>1)*64. Writes one float per block. ----
__global__ __launch_bounds__(256, 2) void kg_main(
    const float* __restrict__ ent, const float* __restrict__ rel,
    const float* __restrict__ M,   const int* __restrict__ h,
    const int* __restrict__ r,     const int* __restrict__ pt,
    const int* __restrict__ nt,    const int* __restrict__ perm,
    float* __restrict__ bsum)
{
    __shared__ unsigned short sX[3 * KG_TM * KG_D];   // 24 KB bf16, row-XOR-swizzled
    __shared__ unsigned short sW[KG_D * KG_D];        // 32 KB bf16 W^T, col-XOR-swizzled
    __shared__ float sScr[2][KG_TM][4];               // score partials

    const int tid   = threadIdx.x;
    const int slot0 = blockIdx.x * KG_TM;
    const int p0    = perm[slot0];
    if (p0 < 0) {                          // fully padded / unused trailing group
        if (tid == 0) bsum[blockIdx.x] = 0.f;
        return;
    }
    const int rb = __builtin_amdgcn_readfirstlane(r[p0]);

    // ---- stage X: thread t -> row g=t>>3, 16 dims at e0=(t&7)*16, 3 products ----
    {
        const int g  = tid >> 3;
        const int e0 = (tid & 7) * 16;
        const int pg = perm[slot0 + g];
        const int bb = pg < 0 ? p0 : pg;
        const int idx3[3] = { h[bb], pt[bb], nt[bb] };
        const int sw = (g & 7) << 3;
#pragma unroll
        for (int t3 = 0; t3 < 3; ++t3) {
            const float* src = ent + (size_t)idx3[t3] * KG_D + e0;
            const float4 f0 = ((const float4*)src)[0];
            const float4 f1 = ((const float4*)src)[1];
            const float4 f2 = ((const float4*)src)[2];
            const float4 f3 = ((const float4*)src)[3];
            uint4 u0, u1;
            u0.x = pack2(f0.x, f0.y); u0.y = pack2(f0.z, f0.w);
            u0.z = pack2(f1.x, f1.y); u0.w = pack2(f1.z, f1.w);
            u1.x = pack2(f2.x, f2.y); u1.y = pack2(f2.z, f2.w);
            u1.z = pack2(f3.x, f3.y); u1.w = pack2(f3.z, f3.w);
            unsigned short* base = sX + t3 * (KG_TM * KG_D) + g * KG_D;
            *(uint4*)(base + ((e0    ) ^ sw)) = u0;
            *(uint4*)(base + ((e0 + 8) ^ sw)) = u1;
        }
    }
    // ---- stage W^T: register transpose. thread t -> W rows e0g..e0g+3,
    //      cols c0..c0+15; packed b64 col-major stores (same layout/swizzle
    //      the MFMA B-reads use). 8-lane-coalesced global reads. ----
    {
        const int e0g = (tid >> 3) * 4;
        const int c0  = (tid & 7) * 16;
        const float* src = M + ((size_t)rb << 14) + (size_t)e0g * KG_D + c0;
        float4 rw[4][4];
#pragma unroll
        for (int dr = 0; dr < 4; ++dr)
#pragma unroll
            for (int f = 0; f < 4; ++f)
                rw[dr][f] = ((const float4*)(src + dr * KG_D))[f];
#pragma unroll
        for (int dc = 0; dc < 16; ++dc) {
            const int col = c0 + dc;
            const float v0 = ((const float*)&rw[0][0])[dc];
            const float v1 = ((const float*)&rw[1][0])[dc];
            const float v2 = ((const float*)&rw[2][0])[dc];
            const float v3 = ((const float*)&rw[3][0])[dc];
            uint2 st;
            st.x = pack2(v0, v1);
            st.y = pack2(v2, v3);
            *(uint2*)&sW[col * KG_D + (e0g ^ ((col & 7) << 3))] = st;
        }
    }
    __syncthreads();

    const int l   = tid & 63;
    const int w   = tid >> 6;
    const int rt  = w & 1;                 // row-tile (16 rows)
    const int chs = w >> 1;                // column half (64 cols)
    const int li  = l & 15;
    const int kq  = l >> 4;

    const int ar  = rt * 16 + li;          // A row = element index in block
    const int asw = (ar & 7) << 3;

    f32x4 acc[3][4];
#pragma unroll
    for (int t3 = 0; t3 < 3; ++t3)
#pragma unroll
        for (int n = 0; n < 4; ++n) acc[t3][n] = (f32x4)0.f;

#pragma unroll
    for (int kk = 0; kk < 4; ++kk) {       // K chunks of 32
        const int e0 = kk * 32 + kq * 8;
        bf16x8 af[3];
#pragma unroll
        for (int t3 = 0; t3 < 3; ++t3)
            af[t3] = *(const bf16x8*)&sX[t3 * (KG_TM * KG_D) + ar * KG_D + (e0 ^ asw)];
#pragma unroll
        for (int n = 0; n < 4; ++n) {
            const int col = chs * 64 + n * 16 + li;
            const bf16x8 bfr = *(const bf16x8*)&sW[col * KG_D + (e0 ^ ((col & 7) << 3))];
            acc[0][n] = __builtin_amdgcn_mfma_f32_16x16x32_bf16(af[0], bfr, acc[0][n], 0, 0, 0);
            acc[1][n] = __builtin_amdgcn_mfma_f32_16x16x32_bf16(af[1], bfr, acc[1][n], 0, 0, 0);
            acc[2][n] = __builtin_amdgcn_mfma_f32_16x16x32_bf16(af[2], bfr, acc[2][n], 0, 0, 0);
        }
    }

    // ---- epilogue: C/D layout col=lane&15, row=(lane>>4)*4+reg ----
    float ps[4] = {0,0,0,0}, ns[4] = {0,0,0,0}, sq[4] = {0,0,0,0};
    const float* relrow = rel + (size_t)rb * KG_D + chs * 64;
#pragma unroll
    for (int n = 0; n < 4; ++n) {
        const float rv = relrow[n * 16 + li];
#pragma unroll
        for (int j = 0; j < 4; ++j) {
            const float va = acc[0][n][j];
            const float vp = acc[1][n][j];
            const float vn = acc[2][n][j];
            const float s  = va + rv;
            const float dp = s - vp;
            const float dn = s - vn;
            ps[j] += dp * dp;
            ns[j] += dn * dn;
            sq[j] += va * va + vp * vp + vn * vn + rv * rv;
        }
    }
#pragma unroll
    for (int j = 0; j < 4; ++j)
#pragma unroll
        for (int m = 1; m < 16; m <<= 1) {
            ps[j] += __shfl_xor(ps[j], m);
            ns[j] += __shfl_xor(ns[j], m);
            sq[j] += __shfl_xor(sq[j], m);
        }

    if (li == 0) {
#pragma unroll
        for (int j = 0; j < 4; ++j) {
            const int row = rt * 16 + kq * 4 + j;
            sScr[chs][row][0] = ps[j];
            sScr[chs][row][1] = ns[j];
            sScr[chs][row][2] = sq[j];
        }
    }
    __syncthreads();

    // ---- per-row term + block sum (wave 0 only) -> bsum[block] ----
    if (tid < 64) {
        float term = 0.f;
        if (tid < KG_TM) {
            const int row = tid;
            const float P = sScr[0][row][0] + sScr[1][row][0];
            const float N = sScr[0][row][1] + sScr[1][row][1];
            const float S = sScr[0][row][2] + sScr[1][row][2];
            const int pg = perm[slot0 + row];
            if (pg >= 0) {
                const float x = P - N;                            // pos - neg
                term = fmaxf(x, 0.f) + log1pf(expf(-fabsf(x)))    // softplus
                     + 5e-6f * S;                                 // lambda/2 * l2
            }
        }
#pragma unroll
        for (int off = 16; off > 0; off >>= 1) term += __shfl_down(term, off);
        if (tid == 0) bsum[blockIdx.x] = term;
    }
}

// ---- K3: deterministic final reduction over 536 block sums ----
__global__ __launch_bounds__(256) void kg_final(const float* __restrict__ bsum,
                                                float* __restrict__ out) {
    __shared__ float s[256];
    const int t = threadIdx.x;
    float acc = 0.f;
    for (int i = t; i < KG_NGRP; i += 256) acc += bsum[i];
    s[t] = acc;
    __syncthreads();
    for (int off = 128; off > 0; off >>= 1) {
        if (t < off) s[t] += s[t + off];
        __syncthreads();
    }
    if (t == 0) out[0] = s[0] * (1.0f / (float)KG_B);
}

extern "C" void kernel_launch(void* const* d_in, const int* in_sizes, int n_in,
                              void* d_out, int out_size, void* d_ws, size_t ws_size,
                              hipStream_t stream) {
    const float* ent = (const float*)d_in[0];
    const float* rel = (const float*)d_in[1];
    const float* M   = (const float*)d_in[2];
    const int*   h   = (const int*)d_in[3];
    const int*   r   = (const int*)d_in[4];
    const int*   pt  = (const int*)d_in[5];
    const int*   nt  = (const int*)d_in[6];

    int*   perm = (int*)d_ws;
    float* bsum = (float*)d_ws + WS_BSUM;
    float* out  = (float*)d_out;

    kg_sort <<<1, 1024, 0, stream>>>(r, perm);
    kg_main <<<KG_NGRP, 256, 0, stream>>>(ent, rel, M, h, r, pt, nt, perm, bsum);
    kg_final<<<1, 256, 0, stream>>>(bsum, out);
}

// Round 7
// 27.889 us; speedup vs baseline: 1.2739x; 1.1548x over previous
//
#include <hip/hip_runtime.h>
#include <math.h>

#define KG_B    16384
#define KG_D    128
#define KG_NR   24
#define KG_TM   32                        // elements per block
#define KG_BPAD (KG_B + KG_NR * KG_TM)    // 17152
#define KG_NGRP (KG_BPAD / KG_TM)         // 536

// ws layout: int perm[KG_BPAD] | float bsum[KG_NGRP] | (at byte 131072) ushort preW[24*16384]
#define WS_BSUM KG_BPAD
#define WS_PREW_BYTES 131072

typedef __attribute__((ext_vector_type(8))) short bf16x8;
typedef __attribute__((ext_vector_type(4))) float f32x4;

__device__ __forceinline__ unsigned bf16r(float f) {
    return (__float_as_uint(f) + 0x8000u) >> 16;
}
__device__ __forceinline__ unsigned pack2(float lo, float hi) {
    return bf16r(lo) | (bf16r(hi) << 16);
}

// ---- K1: block 0 = fused relation sort; blocks 1..24 = W^T bf16 prep  ----
// preW[k] holds W_k^T in bf16 in EXACTLY the swizzled element order kg_main's
// B-reads use: elem j = col*128 + (e ^ ((col&7)<<3))  ->  bf16(W[k][e][col]).
__global__ __launch_bounds__(1024) void kg_sort_prep(const int* __restrict__ r,
                                                     const float* __restrict__ M,
                                                     int* __restrict__ perm,
                                                     unsigned short* __restrict__ preW) {
    __shared__ int cntw[16][25];
    __shared__ int basew[16][25];
    __shared__ int pbase_s[24];
    __shared__ int cnt_tot[24];
    __shared__ int total_s;
    __shared__ __align__(16) unsigned short sWp[KG_D * KG_D];   // 32 KB (prep path)

    const int t = threadIdx.x;

    if (blockIdx.x != 0) {
        // ---------- prep path: transpose+pack one 128x128 matrix ----------
        const int k  = blockIdx.x - 1;
        const int e  = t >> 3;              // 0..127
        const int c0 = (t & 7) * 16;
        const float* src = M + ((size_t)k << 14) + (size_t)e * KG_D + c0;
        float4 rw[4];
#pragma unroll
        for (int f = 0; f < 4; ++f) rw[f] = ((const float4*)src)[f];
#pragma unroll
        for (int dc = 0; dc < 16; ++dc) {
            const int col = c0 + dc;
            const float v = ((const float*)&rw[0])[dc];
            sWp[col * KG_D + (e ^ ((col & 7) << 3))] = (unsigned short)bf16r(v);
        }
        __syncthreads();
        // linear coalesced copy-out: 32 B per thread
        uint4* dst = (uint4*)(preW + ((size_t)k << 14));
        const uint4* s4 = (const uint4*)sWp;
        dst[2 * t]     = s4[2 * t];
        dst[2 * t + 1] = s4[2 * t + 1];
        return;
    }

    // ---------- sort path (single block) ----------
    const int w = t >> 6;
    int* cz = &cntw[0][0];
    for (int i = t; i < 16 * 25; i += 1024) cz[i] = 0;
    __syncthreads();

    int kt[16];
#pragma unroll
    for (int j = 0; j < 16; ++j) kt[j] = r[j * 1024 + t];
#pragma unroll
    for (int j = 0; j < 16; ++j) atomicAdd(&cntw[w][kt[j]], 1);
    __syncthreads();

    if (t < 24) {
        int s = 0;
        for (int w2 = 0; w2 < 16; ++w2) { basew[w2][t] = s; s += cntw[w2][t]; }
        cnt_tot[t] = s;
    }
    __syncthreads();
    if (t == 0) {
        int run = 0;
        for (int k = 0; k < 24; ++k) {
            pbase_s[k] = run;
            run += (cnt_tot[k] + (KG_TM - 1)) & ~(KG_TM - 1);
        }
        total_s = run;
    }
    __syncthreads();
    if (t < 24)
        for (int w2 = 0; w2 < 16; ++w2) basew[w2][t] += pbase_s[t];
    for (int i = t; i < 16 * 25; i += 1024) cz[i] = 0;   // reuse cntw as cur
    __syncthreads();

#pragma unroll
    for (int j = 0; j < 16; ++j) {
        const int k = kt[j];
        const int pos = basew[w][k] + atomicAdd(&cntw[w][k], 1);
        perm[pos] = j * 1024 + t;
    }
    __syncthreads();

    if (t < 24) {
        const int e0 = pbase_s[t] + cnt_tot[t];
        const int e1 = pbase_s[t] + ((cnt_tot[t] + (KG_TM - 1)) & ~(KG_TM - 1));
        for (int p = e0; p < e1; ++p) perm[p] = -1;
    }
    for (int i = total_s + t; i < KG_BPAD; i += 1024) perm[i] = -1;
}

// ---- K2: MFMA main. Block = 32 same-relation elements, 4 waves. ----
__global__ __launch_bounds__(256, 2) void kg_main(
    const float* __restrict__ ent, const float* __restrict__ rel,
    const unsigned short* __restrict__ preW,
    const int* __restrict__ h,     const int* __restrict__ r,
    const int* __restrict__ pt,    const int* __restrict__ nt,
    const int* __restrict__ perm,  float* __restrict__ bsum)
{
    __shared__ __align__(16) unsigned short sX[3 * KG_TM * KG_D];   // 24 KB
    __shared__ __align__(16) unsigned short sW[KG_D * KG_D];        // 32 KB
    __shared__ float sScr[2][KG_TM][4];

    const int tid   = threadIdx.x;
    const int slot0 = blockIdx.x * KG_TM;
    const int p0    = perm[slot0];
    if (p0 < 0) {
        if (tid == 0) bsum[blockIdx.x] = 0.f;
        return;
    }
    const int rb = __builtin_amdgcn_readfirstlane(r[p0]);

    // ---- stage W: async linear copy of the prepped swizzled image ----
    {
        const char* gsrc = (const char*)(preW + ((size_t)rb << 14));
        char* ldsb = (char*)&sW[0];
        const int w4   = tid >> 6;
        const int lane = tid & 63;
#pragma unroll
        for (int q = 0; q < 8; ++q) {
            const int off = q * 4096 + w4 * 1024;
            __builtin_amdgcn_global_load_lds(
                (const unsigned int*)(gsrc + off + lane * 16),
                (unsigned int*)(ldsb + off), 16, 0, 0);
        }
    }

    // ---- stage X: thread t -> row g=t>>3, 16 dims at e0=(t&7)*16, 3 products ----
    {
        const int g  = tid >> 3;
        const int e0 = (tid & 7) * 16;
        const int pg = perm[slot0 + g];
        const int bb = pg < 0 ? p0 : pg;
        const int idx3[3] = { h[bb], pt[bb], nt[bb] };
        const int sw = (g & 7) << 3;
#pragma unroll
        for (int t3 = 0; t3 < 3; ++t3) {
            const float* src = ent + (size_t)idx3[t3] * KG_D + e0;
            const float4 f0 = ((const float4*)src)[0];
            const float4 f1 = ((const float4*)src)[1];
            const float4 f2 = ((const float4*)src)[2];
            const float4 f3 = ((const float4*)src)[3];
            uint4 u0, u1;
            u0.x = pack2(f0.x, f0.y); u0.y = pack2(f0.z, f0.w);
            u0.z = pack2(f1.x, f1.y); u0.w = pack2(f1.z, f1.w);
            u1.x = pack2(f2.x, f2.y); u1.y = pack2(f2.z, f2.w);
            u1.z = pack2(f3.x, f3.y); u1.w = pack2(f3.z, f3.w);
            unsigned short* base = sX + t3 * (KG_TM * KG_D) + g * KG_D;
            *(uint4*)(base + ((e0    ) ^ sw)) = u0;
            *(uint4*)(base + ((e0 + 8) ^ sw)) = u1;
        }
    }
    __syncthreads();   // drains both vmcnt (lds-direct loads) and sX writes

    const int l   = tid & 63;
    const int w   = tid >> 6;
    const int rt  = w & 1;                 // row-tile (16 rows)
    const int chs = w >> 1;                // column half (64 cols)
    const int li  = l & 15;
    const int kq  = l >> 4;

    const int ar  = rt * 16 + li;
    const int asw = (ar & 7) << 3;

    f32x4 acc[3][4];
#pragma unroll
    for (int t3 = 0; t3 < 3; ++t3)
#pragma unroll
        for (int n = 0; n < 4; ++n) acc[t3][n] = (f32x4)0.f;

#pragma unroll
    for (int kk = 0; kk < 4; ++kk) {
        const int e0 = kk * 32 + kq * 8;
        bf16x8 af[3];
#pragma unroll
        for (int t3 = 0; t3 < 3; ++t3)
            af[t3] = *(const bf16x8*)&sX[t3 * (KG_TM * KG_D) + ar * KG_D + (e0 ^ asw)];
#pragma unroll
        for (int n = 0; n < 4; ++n) {
            const int col = chs * 64 + n * 16 + li;
            const bf16x8 bfr = *(const bf16x8*)&sW[col * KG_D + (e0 ^ ((col & 7) << 3))];
            acc[0][n] = __builtin_amdgcn_mfma_f32_16x16x32_bf16(af[0], bfr, acc[0][n], 0, 0, 0);
            acc[1][n] = __builtin_amdgcn_mfma_f32_16x16x32_bf16(af[1], bfr, acc[1][n], 0, 0, 0);
            acc[2][n] = __builtin_amdgcn_mfma_f32_16x16x32_bf16(af[2], bfr, acc[2][n], 0, 0, 0);
        }
    }

    // ---- epilogue: C/D layout col=lane&15, row=(lane>>4)*4+reg ----
    float ps[4] = {0,0,0,0}, ns[4] = {0,0,0,0}, sq[4] = {0,0,0,0};
    const float* relrow = rel + (size_t)rb * KG_D + chs * 64;
#pragma unroll
    for (int n = 0; n < 4; ++n) {
        const float rv = relrow[n * 16 + li];
#pragma unroll
        for (int j = 0; j < 4; ++j) {
            const float va = acc[0][n][j];
            const float vp = acc[1][n][j];
            const float vn = acc[2][n][j];
            const float s  = va + rv;
            const float dp = s - vp;
            const float dn = s - vn;
            ps[j] += dp * dp;
            ns[j] += dn * dn;
            sq[j] += va * va + vp * vp + vn * vn + rv * rv;
        }
    }
#pragma unroll
    for (int j = 0; j < 4; ++j)
#pragma unroll
        for (int m = 1; m < 16; m <<= 1) {
            ps[j] += __shfl_xor(ps[j], m);
            ns[j] += __shfl_xor(ns[j], m);
            sq[j] += __shfl_xor(sq[j], m);
        }

    if (li == 0) {
#pragma unroll
        for (int j = 0; j < 4; ++j) {
            const int row = rt * 16 + kq * 4 + j;
            sScr[chs][row][0] = ps[j];
            sScr[chs][row][1] = ns[j];
            sScr[chs][row][2] = sq[j];
        }
    }
    __syncthreads();

    if (tid < 64) {
        float term = 0.f;
        if (tid < KG_TM) {
            const int row = tid;
            const float P = sScr[0][row][0] + sScr[1][row][0];
            const float N = sScr[0][row][1] + sScr[1][row][1];
            const float S = sScr[0][row][2] + sScr[1][row][2];
            const int pg = perm[slot0 + row];
            if (pg >= 0) {
                const float x = P - N;
                term = fmaxf(x, 0.f) + log1pf(expf(-fabsf(x)))
                     + 5e-6f * S;
            }
        }
#pragma unroll
        for (int off = 16; off > 0; off >>= 1) term += __shfl_down(term, off);
        if (tid == 0) bsum[blockIdx.x] = term;
    }
}

// ---- K3: deterministic final reduction over 536 block sums ----
__global__ __launch_bounds__(256) void kg_final(const float* __restrict__ bsum,
                                                float* __restrict__ out) {
    __shared__ float s[256];
    const int t = threadIdx.x;
    float acc = 0.f;
    for (int i = t; i < KG_NGRP; i += 256) acc += bsum[i];
    s[t] = acc;
    __syncthreads();
    for (int off = 128; off > 0; off >>= 1) {
        if (t < off) s[t] += s[t + off];
        __syncthreads();
    }
    if (t == 0) out[0] = s[0] * (1.0f / (float)KG_B);
}

extern "C" void kernel_launch(void* const* d_in, const int* in_sizes, int n_in,
                              void* d_out, int out_size, void* d_ws, size_t ws_size,
                              hipStream_t stream) {
    const float* ent = (const float*)d_in[0];
    const float* rel = (const float*)d_in[1];
    const float* M   = (const float*)d_in[2];
    const int*   h   = (const int*)d_in[3];
    const int*   r   = (const int*)d_in[4];
    const int*   pt  = (const int*)d_in[5];
    const int*   nt  = (const int*)d_in[6];

    int*            perm = (int*)d_ws;
    float*          bsum = (float*)d_ws + WS_BSUM;
    unsigned short* preW = (unsigned short*)((char*)d_ws + WS_PREW_BYTES);
    float*          out  = (float*)d_out;

    kg_sort_prep<<<1 + KG_NR, 1024, 0, stream>>>(r, M, perm, preW);
    kg_main     <<<KG_NGRP, 256, 0, stream>>>(ent, rel, preW, h, r, pt, nt, perm, bsum);
    kg_final    <<<1, 256, 0, stream>>>(bsum, out);
}